// Round 4
// baseline (5573.244 us; speedup 1.0000x reference)
//
#include <hip/hip_runtime.h>

// LSTM B=64 T=2048 D=H=256.
// FUSED single launch: 120 producer blocks (x@W_i + bias -> xg, fp16) + 8 consumer
// blocks (persistent recurrence, 8 batch rows each). Producers publish per-timestep
// flags (device-scope release); consumers batch-poll every 32 steps.
// Consumer weight residency per CU (round-1/3 layout; 160-reg layouts spill):
//   gate i: fp8 e4m3 in VGPRs (32) | gate f: fp16 in VGPRs (64)
//   gate g: fp16 in LDS (128 KB)   | gate o: fp8 e4m3 in VGPRs (32)
// Duplicate-row trick: A row = n&7 -> quads 2-3 duplicate quads 0-1's C; each lane
// finishes 4 outputs (its own qi tile) -> halved transcendental VALU.
// NEW: no per-step s_barrier. Wave w owns h cols [32w,32w+32) == kt-tile w, so each
// wave publishes an LDS token flag[w]=tt+1 after lgkmcnt(0); readers poll
// min(flags)>=tt. Waves de-lockstep: epilogue of one overlaps MFMAs of another.
// h double-buffered in LDS as fp16 AND fp8 (read buf tt&1, write buf tt&1^1).
// MFMA 16x16x32 (f16 and fp8_fp8): A[m=lane&15][k=(lane>>4)*8+j],
//   B[k][n=lane&15], C row=(lane>>4)*4+reg, col=lane&15.

#define T_ALL 2048
#define NBATCH 64
#define HD 256
#define NG 1024
#define NPROD 120
#define HS_N ((size_t)NBATCH * T_ALL * HD)

typedef _Float16 h8 __attribute__((ext_vector_type(8)));
typedef _Float16 h4 __attribute__((ext_vector_type(4)));
typedef float f4 __attribute__((ext_vector_type(4)));

#define SMEM_W 131072                 // g-gate: 16 tiles x [8kt][64 lanes][8 halfs]
#define SMEM_H 4224                   // h fp16: 8 rows x 264 halfs
#define SMEM_H8 2112                  // h fp8:  8 rows x 264 bytes
#define SMEM_FLG 64                   // 8 wave-token flags (padded)
#define SMEM_TOTAL (SMEM_W + 2 * SMEM_H + 2 * SMEM_H8 + SMEM_FLG)  // 143808 <= 163840

__device__ __forceinline__ float sigf(float x) {
  return __builtin_amdgcn_rcpf(1.f + __expf(-x));
}
__device__ __forceinline__ float tanh_f(float x) {
  return 2.f * __builtin_amdgcn_rcpf(1.f + __expf(-2.f * x)) - 1.f;
}
__device__ __forceinline__ unsigned char to_fp8(float x) {
  return (unsigned char)(__builtin_amdgcn_cvt_pk_fp8_f32(x, x, 0, false) & 0xFF);
}
__device__ __forceinline__ int imin2(int a, int b) { return a < b ? a : b; }

// ---------------- producer: input projection for timesteps t = p mod NPROD ----------
__device__ __forceinline__ void producer_body(
    const float* __restrict__ x, const float* __restrict__ Wi,
    const float* __restrict__ bias, _Float16* __restrict__ xg, int* gflags)
{
  const int tid = threadIdx.x;
  const int w = tid >> 6, L = tid & 63;
  const int n = L & 15, quad = L >> 4;

  for (int t = blockIdx.x; t < T_ALL; t += NPROD) {
    // B-fragments: x^T[k][b], reused across all j tiles (32 frags = 128 VGPRs)
    h8 bx[8][4];
#pragma unroll
    for (int kt = 0; kt < 8; ++kt) {
#pragma unroll
      for (int bt = 0; bt < 4; ++bt) {
        const int b = bt * 16 + n, k = kt * 32 + quad * 8;
        const float* p = x + ((size_t)b * T_ALL + t) * HD + k;
        f4 lo = *(const f4*)p, hi = *(const f4*)(p + 4);
        h8 f;
        f[0] = (_Float16)lo[0]; f[1] = (_Float16)lo[1];
        f[2] = (_Float16)lo[2]; f[3] = (_Float16)lo[3];
        f[4] = (_Float16)hi[0]; f[5] = (_Float16)hi[1];
        f[6] = (_Float16)hi[2]; f[7] = (_Float16)hi[3];
        bx[kt][bt] = f;
      }
    }

    for (int i = 0; i < 8; ++i) {      // wave w owns j-tiles w*8 .. w*8+7
      const int jt = w * 8 + i;
      float bv0 = bias[jt * 16 + quad * 4 + 0];
      float bv1 = bias[jt * 16 + quad * 4 + 1];
      float bv2 = bias[jt * 16 + quad * 4 + 2];
      float bv3 = bias[jt * 16 + quad * 4 + 3];
      f4 acc[4];
#pragma unroll
      for (int bt = 0; bt < 4; ++bt) {
        acc[bt][0] = bv0; acc[bt][1] = bv1; acc[bt][2] = bv2; acc[bt][3] = bv3;
      }
#pragma unroll
      for (int kt = 0; kt < 8; ++kt) {
        const int j = jt * 16 + n, kb = kt * 32 + quad * 8;
        h8 a;   // A = Wi^T: A[m=j][k=d] = Wi[d][j]
#pragma unroll
        for (int jj = 0; jj < 8; ++jj) a[jj] = (_Float16)Wi[(size_t)(kb + jj) * NG + j];
#pragma unroll
        for (int bt = 0; bt < 4; ++bt)
          acc[bt] = __builtin_amdgcn_mfma_f32_16x16x32_f16(a, bx[kt][bt], acc[bt], 0, 0, 0);
      }
#pragma unroll
      for (int bt = 0; bt < 4; ++bt) {
#pragma unroll
        for (int r = 0; r < 4; ++r) {
          const int j = jt * 16 + quad * 4 + r;   // gate col
          xg[(((size_t)t * 4 + bt) * NG + j) * 16 + n] = (_Float16)acc[bt][r];
        }
      }
    }
    __syncthreads();                   // all waves' xg stores drained (vmcnt 0)
    if (tid == 0) {
      __threadfence();                 // agent-scope release: L2 writeback
      __hip_atomic_store(&gflags[t], 1, __ATOMIC_RELAXED, __HIP_MEMORY_SCOPE_AGENT);
    }
  }
}

// ---------------- consumer: persistent recurrence, 8 batch rows per block ----------
__device__ __forceinline__ void recur_body(
    const _Float16* __restrict__ xg, const float* __restrict__ Wh,
    float* __restrict__ out, _Float16* __restrict__ ws_h, float* __restrict__ ws_c,
    const int* gflags, int t0, int CT, int cb, char* smem)
{
  _Float16* w_lds = (_Float16*)smem;                              // g-gate tiles
  int* flg = (int*)(smem + SMEM_W + 2 * SMEM_H + 2 * SMEM_H8);    // 8 wave tokens

  const int tid = threadIdx.x;
  const int w = tid >> 6, L = tid & 63;
  const int n = L & 15, quad = L >> 4;
  const int myqi = L >> 5;             // 0 for quads 0-1, 1 for quads 2-3
  const int mrow4 = ((L >> 4) & 1) * 4;
  const int b_base = cb * 8;
  const int bb8 = (cb & 1) * 8;        // row offset within the 16-batch xg tile

  // ---- load resident weights (one-time) ----
  h8  bF[2][8];                    // f gate fp16: 64 VGPRs
  long bI[2][8], bO[2][8];         // i / o gates fp8 packed: 32 + 32 VGPRs
#pragma unroll
  for (int qi = 0; qi < 2; ++qi) {
    const int q = 2 * w + qi;
    for (int kt = 0; kt < 8; ++kt) {
      const int kb = kt * 32 + quad * 8;
      { // f gate, fp16 regs
        const int j = 256 + q * 16 + n;
        h8 f;
#pragma unroll
        for (int jj = 0; jj < 8; ++jj) f[jj] = (_Float16)Wh[(size_t)(kb + jj) * NG + j];
        bF[qi][kt] = f;
      }
      { // i gate, fp8 regs
        const int j = 0 + q * 16 + n;
        unsigned lo = 0, hi = 0;
        lo = __builtin_amdgcn_cvt_pk_fp8_f32(Wh[(size_t)(kb + 0) * NG + j], Wh[(size_t)(kb + 1) * NG + j], lo, false);
        lo = __builtin_amdgcn_cvt_pk_fp8_f32(Wh[(size_t)(kb + 2) * NG + j], Wh[(size_t)(kb + 3) * NG + j], lo, true);
        hi = __builtin_amdgcn_cvt_pk_fp8_f32(Wh[(size_t)(kb + 4) * NG + j], Wh[(size_t)(kb + 5) * NG + j], hi, false);
        hi = __builtin_amdgcn_cvt_pk_fp8_f32(Wh[(size_t)(kb + 6) * NG + j], Wh[(size_t)(kb + 7) * NG + j], hi, true);
        bI[qi][kt] = (long)(((unsigned long)hi << 32) | (unsigned long)lo);
      }
      { // o gate, fp8 regs
        const int j = 768 + q * 16 + n;
        unsigned lo = 0, hi = 0;
        lo = __builtin_amdgcn_cvt_pk_fp8_f32(Wh[(size_t)(kb + 0) * NG + j], Wh[(size_t)(kb + 1) * NG + j], lo, false);
        lo = __builtin_amdgcn_cvt_pk_fp8_f32(Wh[(size_t)(kb + 2) * NG + j], Wh[(size_t)(kb + 3) * NG + j], lo, true);
        hi = __builtin_amdgcn_cvt_pk_fp8_f32(Wh[(size_t)(kb + 4) * NG + j], Wh[(size_t)(kb + 5) * NG + j], hi, false);
        hi = __builtin_amdgcn_cvt_pk_fp8_f32(Wh[(size_t)(kb + 6) * NG + j], Wh[(size_t)(kb + 7) * NG + j], hi, true);
        bO[qi][kt] = (long)(((unsigned long)hi << 32) | (unsigned long)lo);
      }
      { // g gate -> LDS
        const int j = 512 + q * 16 + n;
        h8 f;
#pragma unroll
        for (int jj = 0; jj < 8; ++jj) f[jj] = (_Float16)Wh[(size_t)(kb + jj) * NG + j];
        *(h8*)(w_lds + ((size_t)(q * 8 + kt) * 64 + L) * 8) = f;
      }
    }
  }

  // ---- state init / restore (into buffer 0: read buffer of step tt=0) ----
  _Float16* h0 = (_Float16*)(smem + SMEM_W);
  unsigned char* h80 = (unsigned char*)(smem + SMEM_W + 2 * SMEM_H);
  float creg[4];                    // lane-private c: row=mrow4+r, col=(2w+myqi)*16+n
  const int c_col = (2 * w + myqi) * 16 + n;
  if (tid < 8) flg[tid] = 0;
  if (t0 == 0) {
    for (int i = tid; i < 8 * 264; i += 512) h0[i] = (_Float16)0.f;
    for (int i = tid * 4; i < 8 * 264; i += 512 * 4) *(unsigned*)(h80 + i) = 0u;
#pragma unroll
    for (int i = 0; i < 4; ++i) creg[i] = 0.f;
  } else {
    if (tid < 256) {
      const int idx = tid * 8, r = idx >> 8, c = idx & 255;
      h8 hv = *(const h8*)(ws_h + (size_t)(b_base + r) * HD + c);
      *(h8*)(h0 + r * 264 + c) = hv;
      unsigned lo = 0, hi = 0;
      lo = __builtin_amdgcn_cvt_pk_fp8_f32((float)hv[0], (float)hv[1], lo, false);
      lo = __builtin_amdgcn_cvt_pk_fp8_f32((float)hv[2], (float)hv[3], lo, true);
      hi = __builtin_amdgcn_cvt_pk_fp8_f32((float)hv[4], (float)hv[5], hi, false);
      hi = __builtin_amdgcn_cvt_pk_fp8_f32((float)hv[6], (float)hv[7], hi, true);
      *(unsigned*)(h80 + r * 264 + c) = lo;
      *(unsigned*)(h80 + r * 264 + c + 4) = hi;
    }
#pragma unroll
    for (int r2 = 0; r2 < 4; ++r2)
      creg[r2] = ws_c[(size_t)(b_base + mrow4 + r2) * HD + c_col];
  }
  __syncthreads();

  // ---- precomputed addressing ----
  // A-fragment row = n&7: rows 8-15 duplicate rows 0-7 (broadcast).
  const int a16_off = (n & 7) * 264 + quad * 8;     // h fp16 read offset (halfs)
  const int a8_off  = (n & 7) * 264 + quad * 8;     // h fp8 read offset (bytes)
  int loff[4];                                       // xq for THIS lane's qi only
#pragma unroll
  for (int g = 0; g < 4; ++g)
    loff[g] = ((g * 256 + c_col) << 4) + bb8 + mrow4;
  const _Float16* xgp = xg + (size_t)(cb >> 1) * (NG * 16);
  float* po[4];
#pragma unroll
  for (int r = 0; r < 4; ++r)
    po[r] = out + ((size_t)(b_base + mrow4 + r) * T_ALL + t0) * HD + c_col;

#pragma unroll 1
  for (int tt = 0; tt < CT; ++tt) {
    // producer readiness (fused mode): batch-poll 32 timestep flags, then acquire.
    if (gflags != nullptr && (tt & 31) == 0) {
      const int hi2 = imin2(tt + 32, CT);
      for (int t2 = t0 + tt; t2 < t0 + hi2; ++t2) {
        while (__hip_atomic_load(&gflags[t2], __ATOMIC_RELAXED, __HIP_MEMORY_SCOPE_AGENT) == 0)
          __builtin_amdgcn_s_sleep(8);
      }
      __threadfence();                 // acquire: invalidate stale cache state
    }

    const int p = tt & 1;
    const _Float16* hr = (const _Float16*)(smem + SMEM_W + p * SMEM_H);
    const unsigned char* h8r = (const unsigned char*)(smem + SMEM_W + 2 * SMEM_H + p * SMEM_H8);
    _Float16* hw = (_Float16*)(smem + SMEM_W + (p ^ 1) * SMEM_H);
    unsigned char* h8w = (unsigned char*)(smem + SMEM_W + 2 * SMEM_H + (p ^ 1) * SMEM_H8);

    h4 xq[4];
#pragma unroll
    for (int g = 0; g < 4; ++g) xq[g] = *(const h4*)(xgp + loff[g]);

    // wave-token wait: all waves published h(tt) (flag[w] >= tt).
    {
      const volatile int* vf = flg;
      for (;;) {
        int a0 = vf[0], a1 = vf[1], a2 = vf[2], a3 = vf[3];
        int a4 = vf[4], a5 = vf[5], a6 = vf[6], a7 = vf[7];
        int m0 = imin2(imin2(a0, a1), imin2(a2, a3));
        int m1 = imin2(imin2(a4, a5), imin2(a6, a7));
        if (imin2(m0, m1) >= tt) break;
        __builtin_amdgcn_s_sleep(1);
      }
    }
    asm volatile("" ::: "memory");
    __builtin_amdgcn_sched_barrier(0);   // keep h reads below the poll

    f4 aI[2], aF[2], aG[2], aO[2];
#pragma unroll
    for (int qi = 0; qi < 2; ++qi) {
      aI[qi][0]=0.f; aI[qi][1]=0.f; aI[qi][2]=0.f; aI[qi][3]=0.f;
      aF[qi][0]=0.f; aF[qi][1]=0.f; aF[qi][2]=0.f; aF[qi][3]=0.f;
      aG[qi][0]=0.f; aG[qi][1]=0.f; aG[qi][2]=0.f; aG[qi][3]=0.f;
      aO[qi][0]=0.f; aO[qi][1]=0.f; aO[qi][2]=0.f; aO[qi][3]=0.f;
    }

    __builtin_amdgcn_s_setprio(1);
#pragma unroll
    for (int kt = 0; kt < 8; ++kt) {
      h8  a16 = *(const h8*)(hr + a16_off + kt * 32);
      long a8 = *(const long*)(h8r + a8_off + kt * 32);
      h8 bg0 = *(const h8*)(w_lds + ((size_t)((2 * w + 0) * 8 + kt) * 64 + L) * 8);
      h8 bg1 = *(const h8*)(w_lds + ((size_t)((2 * w + 1) * 8 + kt) * 64 + L) * 8);
      aF[0] = __builtin_amdgcn_mfma_f32_16x16x32_f16(a16, bF[0][kt], aF[0], 0, 0, 0);
      aF[1] = __builtin_amdgcn_mfma_f32_16x16x32_f16(a16, bF[1][kt], aF[1], 0, 0, 0);
      aG[0] = __builtin_amdgcn_mfma_f32_16x16x32_f16(a16, bg0, aG[0], 0, 0, 0);
      aG[1] = __builtin_amdgcn_mfma_f32_16x16x32_f16(a16, bg1, aG[1], 0, 0, 0);
      aI[0] = __builtin_amdgcn_mfma_f32_16x16x32_fp8_fp8(a8, bI[0][kt], aI[0], 0, 0, 0);
      aI[1] = __builtin_amdgcn_mfma_f32_16x16x32_fp8_fp8(a8, bI[1][kt], aI[1], 0, 0, 0);
      aO[0] = __builtin_amdgcn_mfma_f32_16x16x32_fp8_fp8(a8, bO[0][kt], aO[0], 0, 0, 0);
      aO[1] = __builtin_amdgcn_mfma_f32_16x16x32_fp8_fp8(a8, bO[1][kt], aO[1], 0, 0, 0);
    }
    __builtin_amdgcn_s_setprio(0);

    // Epilogue: 4 outputs/lane (own qi tile via duplicate C-fragments).
    const bool hiq = (L & 32) != 0;
    const f4 sI = hiq ? aI[1] : aI[0];
    const f4 sF = hiq ? aF[1] : aF[0];
    const f4 sG = hiq ? aG[1] : aG[0];
    const f4 sO = hiq ? aO[1] : aO[0];
#pragma unroll
    for (int r = 0; r < 4; ++r) {
      const int row = mrow4 + r;
      const float vi = sI[r] + (float)xq[0][r];
      const float vf = sF[r] + (float)xq[1][r];
      const float vg = sG[r] + (float)xq[2][r];
      const float vo = sO[r] + (float)xq[3][r];
      const float cn = sigf(vf) * creg[r] + sigf(vi) * tanh_f(vg);
      const float hn = sigf(vo) * tanh_f(cn);
      creg[r] = cn;
      hw[row * 264 + c_col] = (_Float16)hn;
      h8w[row * 264 + c_col] = to_fp8(hn);
      __builtin_nontemporal_store(hn, po[r]);
    }
#pragma unroll
    for (int r = 0; r < 4; ++r) po[r] += HD;
    xgp += 4 * NG * 16;

    // publish: h writes drained, then this wave's token (no barrier, no vmcnt drain).
    asm volatile("s_waitcnt lgkmcnt(0)" ::: "memory");
    __builtin_amdgcn_sched_barrier(0);
    if (L == 0) ((volatile int*)flg)[w] = tt + 1;
  }
  __syncthreads();

  { // persist state for next chunk + final h_T/c_T
    const int pf = CT & 1;   // buffer holding h(t0+CT-1)
    const _Float16* hfin = (const _Float16*)(smem + SMEM_W + pf * SMEM_H);
    if (tid < 256) {
      const int idx = tid * 8, r = idx >> 8, c = idx & 255;
      h8 hv = *(const h8*)(hfin + r * 264 + c);
      *(h8*)(ws_h + (size_t)(b_base + r) * HD + c) = hv;
      if (t0 + CT == T_ALL) {
        float* ph = out + HS_N + (size_t)(b_base + r) * HD + c;
#pragma unroll
        for (int j = 0; j < 8; ++j) ph[j] = (float)hv[j];
      }
    }
#pragma unroll
    for (int r2 = 0; r2 < 4; ++r2)
      ws_c[(size_t)(b_base + mrow4 + r2) * HD + c_col] = creg[r2];

    if (t0 + CT == T_ALL) {
#pragma unroll
      for (int r2 = 0; r2 < 4; ++r2)
        out[HS_N + (size_t)NBATCH * HD +
            (size_t)(b_base + mrow4 + r2) * HD + c_col] = creg[r2];
    }
  }
}

// ---------------- kernels ----------------
__global__ void clear_flags(int* f) {
  f[blockIdx.x * 1024 + threadIdx.x] = 0;
}

__global__ __launch_bounds__(512, 2) void lstm_fused(
    const float* __restrict__ x, const float* __restrict__ Wi,
    const float* __restrict__ bias, const float* __restrict__ Wh,
    _Float16* __restrict__ xg, float* __restrict__ out,
    _Float16* __restrict__ ws_h, float* __restrict__ ws_c, int* gflags)
{
  extern __shared__ char smem[];
  if (blockIdx.x < NPROD) {
    producer_body(x, Wi, bias, xg, gflags);
  } else {
    recur_body(xg, Wh, out, ws_h, ws_c, gflags, 0, T_ALL, blockIdx.x - NPROD, smem);
  }
}

// fallback path (workspace too small for full-T xg): chunked two-kernel pipeline
__global__ __launch_bounds__(256, 2) void lstm_proj(
    const float* __restrict__ x, const float* __restrict__ Wi,
    const float* __restrict__ bias, _Float16* __restrict__ xg, int t0)
{
  const int t = t0 + blockIdx.x;
  const int tid = threadIdx.x;
  const int w = tid >> 6, L = tid & 63;
  const int n = L & 15, quad = L >> 4;

  h8 bx[8][4];
#pragma unroll
  for (int kt = 0; kt < 8; ++kt) {
#pragma unroll
    for (int bt = 0; bt < 4; ++bt) {
      const int b = bt * 16 + n, k = kt * 32 + quad * 8;
      const float* p = x + ((size_t)b * T_ALL + t) * HD + k;
      f4 lo = *(const f4*)p, hi = *(const f4*)(p + 4);
      h8 f;
      f[0] = (_Float16)lo[0]; f[1] = (_Float16)lo[1];
      f[2] = (_Float16)lo[2]; f[3] = (_Float16)lo[3];
      f[4] = (_Float16)hi[0]; f[5] = (_Float16)hi[1];
      f[6] = (_Float16)hi[2]; f[7] = (_Float16)hi[3];
      bx[kt][bt] = f;
    }
  }

  for (int i = 0; i < 16; ++i) {
    const int jt = w * 16 + i;
    float bv0 = bias[jt * 16 + quad * 4 + 0];
    float bv1 = bias[jt * 16 + quad * 4 + 1];
    float bv2 = bias[jt * 16 + quad * 4 + 2];
    float bv3 = bias[jt * 16 + quad * 4 + 3];
    f4 acc[4];
#pragma unroll
    for (int bt = 0; bt < 4; ++bt) {
      acc[bt][0] = bv0; acc[bt][1] = bv1; acc[bt][2] = bv2; acc[bt][3] = bv3;
    }
#pragma unroll
    for (int kt = 0; kt < 8; ++kt) {
      const int j = jt * 16 + n, kb = kt * 32 + quad * 8;
      h8 a;
#pragma unroll
      for (int jj = 0; jj < 8; ++jj) a[jj] = (_Float16)Wi[(size_t)(kb + jj) * NG + j];
#pragma unroll
      for (int bt = 0; bt < 4; ++bt)
        acc[bt] = __builtin_amdgcn_mfma_f32_16x16x32_f16(a, bx[kt][bt], acc[bt], 0, 0, 0);
    }
#pragma unroll
    for (int bt = 0; bt < 4; ++bt) {
#pragma unroll
      for (int r = 0; r < 4; ++r) {
        const int j = jt * 16 + quad * 4 + r;
        xg[(((size_t)blockIdx.x * 4 + bt) * NG + j) * 16 + n] = (_Float16)acc[bt][r];
      }
    }
  }
}

__global__ __launch_bounds__(512, 2) void lstm_recur(
    const _Float16* __restrict__ xg, const float* __restrict__ Wh,
    float* __restrict__ out, _Float16* __restrict__ ws_h, float* __restrict__ ws_c,
    int t0, int CT)
{
  extern __shared__ char smem[];
  recur_body(xg, Wh, out, ws_h, ws_c, nullptr, t0, CT, blockIdx.x, smem);
}

extern "C" void kernel_launch(void* const* d_in, const int* in_sizes, int n_in,
                              void* d_out, int out_size, void* d_ws, size_t ws_size,
                              hipStream_t stream) {
  (void)in_sizes; (void)n_in; (void)out_size;
  const float* x    = (const float*)d_in[0];
  const float* Wi   = (const float*)d_in[1];
  const float* Wh   = (const float*)d_in[2];
  const float* bias = (const float*)d_in[3];
  float* out = (float*)d_out;

  const size_t state_bytes = (size_t)NBATCH * HD * 2 + (size_t)NBATCH * HD * 4
                           + (size_t)T_ALL * 4;
  int CT = T_ALL;
  while (CT > 32 && (size_t)CT * NG * 64 * 2 + state_bytes > ws_size) CT >>= 1;

  _Float16* xg   = (_Float16*)d_ws;
  _Float16* ws_h = (_Float16*)((char*)d_ws + (size_t)CT * NG * 64 * 2);
  float*    ws_c = (float*)((char*)ws_h + (size_t)NBATCH * HD * 2);
  int*    gflags = (int*)((char*)ws_c + (size_t)NBATCH * HD * 4);

  (void)hipFuncSetAttribute((const void*)lstm_fused,
                            hipFuncAttributeMaxDynamicSharedMemorySize, SMEM_TOTAL);
  (void)hipFuncSetAttribute((const void*)lstm_recur,
                            hipFuncAttributeMaxDynamicSharedMemorySize, SMEM_TOTAL);

  if (CT == T_ALL) {
    clear_flags<<<dim3(2), dim3(1024), 0, stream>>>(gflags);
    lstm_fused<<<dim3(NPROD + 8), dim3(512), SMEM_TOTAL, stream>>>(
        x, Wi, bias, Wh, xg, out, ws_h, ws_c, gflags);
  } else {
    for (int t0 = 0; t0 < T_ALL; t0 += CT) {
      lstm_proj<<<dim3(CT), dim3(256), 0, stream>>>(x, Wi, bias, xg, t0);
      lstm_recur<<<dim3(8), dim3(512), SMEM_TOTAL, stream>>>(xg, Wh, out, ws_h, ws_c, t0, CT);
    }
  }
}

// Round 5
// 4268.019 us; speedup vs baseline: 1.3058x; 1.3058x over previous
//
#include <hip/hip_runtime.h>

// LSTM B=64 T=2048 D=H=256.
// FUSED single launch: 120 producer blocks (x@W_i + bias -> xg, fp16) + 8 consumer
// blocks (persistent recurrence, 8 batch rows each). Producers publish per-timestep
// flags (release fence + agent-scope store); consumers batch-check 32 flags with
// UNROLLED INDEPENDENT loads (round-4's serialized per-flag poll cost ~375 cyc/step).
// Consumer step loop is exactly round-3's proven structure:
//   hardware s_barrier per step with lgkmcnt(0)-only drain (no vmcnt drain).
// Consumer weight residency per CU (160-reg layouts spill; VGPR cap 128):
//   gate i: fp8 e4m3 in VGPRs (32) | gate f: fp16 in VGPRs (64)
//   gate g: fp16 in LDS (128 KB)   | gate o: fp8 e4m3 in VGPRs (32)
// Duplicate-row trick: A row = n&7 -> quads 2-3 duplicate quads 0-1's C; each lane
// finishes 4 outputs (own qi tile) -> halved transcendental VALU.
// h double-buffered in LDS as fp16 AND fp8 (read buf tt&1, write buf tt&1^1).
// MFMA 16x16x32 (f16 and fp8_fp8): A[m=lane&15][k=(lane>>4)*8+j],
//   B[k][n=lane&15], C row=(lane>>4)*4+reg, col=lane&15.

#define T_ALL 2048
#define NBATCH 64
#define HD 256
#define NG 1024
#define NPROD 120
#define HS_N ((size_t)NBATCH * T_ALL * HD)

typedef _Float16 h8 __attribute__((ext_vector_type(8)));
typedef _Float16 h4 __attribute__((ext_vector_type(4)));
typedef float f4 __attribute__((ext_vector_type(4)));

#define SMEM_W 131072                 // g-gate: 16 tiles x [8kt][64 lanes][8 halfs]
#define SMEM_H 4224                   // h fp16: 8 rows x 264 halfs
#define SMEM_H8 2112                  // h fp8:  8 rows x 264 bytes
#define SMEM_TOTAL (SMEM_W + 2 * SMEM_H + 2 * SMEM_H8)   // 143744 <= 163840

__device__ __forceinline__ float sigf(float x) {
  return __builtin_amdgcn_rcpf(1.f + __expf(-x));
}
__device__ __forceinline__ float tanh_f(float x) {
  return 2.f * __builtin_amdgcn_rcpf(1.f + __expf(-2.f * x)) - 1.f;
}
__device__ __forceinline__ unsigned char to_fp8(float x) {
  return (unsigned char)(__builtin_amdgcn_cvt_pk_fp8_f32(x, x, 0, false) & 0xFF);
}
__device__ __forceinline__ int imin2(int a, int b) { return a < b ? a : b; }

// ---------------- producer: input projection for timesteps t = p mod NPROD ----------
__device__ __forceinline__ void producer_body(
    const float* __restrict__ x, const float* __restrict__ Wi,
    const float* __restrict__ bias, _Float16* __restrict__ xg, int* gflags)
{
  const int tid = threadIdx.x;
  const int w = tid >> 6, L = tid & 63;
  const int n = L & 15, quad = L >> 4;

  for (int t = blockIdx.x; t < T_ALL; t += NPROD) {
    // B-fragments: x^T[k][b], reused across all j tiles (32 frags = 128 VGPRs)
    h8 bx[8][4];
#pragma unroll
    for (int kt = 0; kt < 8; ++kt) {
#pragma unroll
      for (int bt = 0; bt < 4; ++bt) {
        const int b = bt * 16 + n, k = kt * 32 + quad * 8;
        const float* p = x + ((size_t)b * T_ALL + t) * HD + k;
        f4 lo = *(const f4*)p, hi = *(const f4*)(p + 4);
        h8 f;
        f[0] = (_Float16)lo[0]; f[1] = (_Float16)lo[1];
        f[2] = (_Float16)lo[2]; f[3] = (_Float16)lo[3];
        f[4] = (_Float16)hi[0]; f[5] = (_Float16)hi[1];
        f[6] = (_Float16)hi[2]; f[7] = (_Float16)hi[3];
        bx[kt][bt] = f;
      }
    }

    for (int i = 0; i < 8; ++i) {      // wave w owns j-tiles w*8 .. w*8+7
      const int jt = w * 8 + i;
      float bv0 = bias[jt * 16 + quad * 4 + 0];
      float bv1 = bias[jt * 16 + quad * 4 + 1];
      float bv2 = bias[jt * 16 + quad * 4 + 2];
      float bv3 = bias[jt * 16 + quad * 4 + 3];
      f4 acc[4];
#pragma unroll
      for (int bt = 0; bt < 4; ++bt) {
        acc[bt][0] = bv0; acc[bt][1] = bv1; acc[bt][2] = bv2; acc[bt][3] = bv3;
      }
#pragma unroll
      for (int kt = 0; kt < 8; ++kt) {
        const int j = jt * 16 + n, kb = kt * 32 + quad * 8;
        h8 a;   // A = Wi^T: A[m=j][k=d] = Wi[d][j]
#pragma unroll
        for (int jj = 0; jj < 8; ++jj) a[jj] = (_Float16)Wi[(size_t)(kb + jj) * NG + j];
#pragma unroll
        for (int bt = 0; bt < 4; ++bt)
          acc[bt] = __builtin_amdgcn_mfma_f32_16x16x32_f16(a, bx[kt][bt], acc[bt], 0, 0, 0);
      }
#pragma unroll
      for (int bt = 0; bt < 4; ++bt) {
#pragma unroll
        for (int r = 0; r < 4; ++r) {
          const int j = jt * 16 + quad * 4 + r;   // gate col
          xg[(((size_t)t * 4 + bt) * NG + j) * 16 + n] = (_Float16)acc[bt][r];
        }
      }
    }
    __syncthreads();                   // all waves' xg stores drained (vmcnt 0)
    if (tid == 0) {
      __threadfence();                 // agent-scope release: L2 writeback
      __hip_atomic_store(&gflags[t], 1, __ATOMIC_RELAXED, __HIP_MEMORY_SCOPE_AGENT);
    }
  }
}

// ---------------- consumer: persistent recurrence, 8 batch rows per block ----------
__device__ __forceinline__ void recur_body(
    const _Float16* __restrict__ xg, const float* __restrict__ Wh,
    float* __restrict__ out, _Float16* __restrict__ ws_h, float* __restrict__ ws_c,
    const int* gflags, int t0, int CT, int cb, char* smem)
{
  _Float16* w_lds = (_Float16*)smem;                              // g-gate tiles

  const int tid = threadIdx.x;
  const int w = tid >> 6, L = tid & 63;
  const int n = L & 15, quad = L >> 4;
  const int myqi = L >> 5;             // 0 for quads 0-1, 1 for quads 2-3
  const int mrow4 = ((L >> 4) & 1) * 4;
  const int b_base = cb * 8;
  const int bb8 = (cb & 1) * 8;        // row offset within the 16-batch xg tile

  // ---- load resident weights (one-time) ----
  h8  bF[2][8];                    // f gate fp16: 64 VGPRs
  long bI[2][8], bO[2][8];         // i / o gates fp8 packed: 32 + 32 VGPRs
#pragma unroll
  for (int qi = 0; qi < 2; ++qi) {
    const int q = 2 * w + qi;
    for (int kt = 0; kt < 8; ++kt) {
      const int kb = kt * 32 + quad * 8;
      { // f gate, fp16 regs
        const int j = 256 + q * 16 + n;
        h8 f;
#pragma unroll
        for (int jj = 0; jj < 8; ++jj) f[jj] = (_Float16)Wh[(size_t)(kb + jj) * NG + j];
        bF[qi][kt] = f;
      }
      { // i gate, fp8 regs
        const int j = 0 + q * 16 + n;
        unsigned lo = 0, hi = 0;
        lo = __builtin_amdgcn_cvt_pk_fp8_f32(Wh[(size_t)(kb + 0) * NG + j], Wh[(size_t)(kb + 1) * NG + j], lo, false);
        lo = __builtin_amdgcn_cvt_pk_fp8_f32(Wh[(size_t)(kb + 2) * NG + j], Wh[(size_t)(kb + 3) * NG + j], lo, true);
        hi = __builtin_amdgcn_cvt_pk_fp8_f32(Wh[(size_t)(kb + 4) * NG + j], Wh[(size_t)(kb + 5) * NG + j], hi, false);
        hi = __builtin_amdgcn_cvt_pk_fp8_f32(Wh[(size_t)(kb + 6) * NG + j], Wh[(size_t)(kb + 7) * NG + j], hi, true);
        bI[qi][kt] = (long)(((unsigned long)hi << 32) | (unsigned long)lo);
      }
      { // o gate, fp8 regs
        const int j = 768 + q * 16 + n;
        unsigned lo = 0, hi = 0;
        lo = __builtin_amdgcn_cvt_pk_fp8_f32(Wh[(size_t)(kb + 0) * NG + j], Wh[(size_t)(kb + 1) * NG + j], lo, false);
        lo = __builtin_amdgcn_cvt_pk_fp8_f32(Wh[(size_t)(kb + 2) * NG + j], Wh[(size_t)(kb + 3) * NG + j], lo, true);
        hi = __builtin_amdgcn_cvt_pk_fp8_f32(Wh[(size_t)(kb + 4) * NG + j], Wh[(size_t)(kb + 5) * NG + j], hi, false);
        hi = __builtin_amdgcn_cvt_pk_fp8_f32(Wh[(size_t)(kb + 6) * NG + j], Wh[(size_t)(kb + 7) * NG + j], hi, true);
        bO[qi][kt] = (long)(((unsigned long)hi << 32) | (unsigned long)lo);
      }
      { // g gate -> LDS
        const int j = 512 + q * 16 + n;
        h8 f;
#pragma unroll
        for (int jj = 0; jj < 8; ++jj) f[jj] = (_Float16)Wh[(size_t)(kb + jj) * NG + j];
        *(h8*)(w_lds + ((size_t)(q * 8 + kt) * 64 + L) * 8) = f;
      }
    }
  }

  // ---- state init / restore (into buffer 0: read buffer of step tt=0) ----
  _Float16* h0 = (_Float16*)(smem + SMEM_W);
  unsigned char* h80 = (unsigned char*)(smem + SMEM_W + 2 * SMEM_H);
  float creg[4];                    // lane-private c: row=mrow4+r, col=(2w+myqi)*16+n
  const int c_col = (2 * w + myqi) * 16 + n;
  if (t0 == 0) {
    for (int i = tid; i < 8 * 264; i += 512) h0[i] = (_Float16)0.f;
    for (int i = tid * 4; i < 8 * 264; i += 512 * 4) *(unsigned*)(h80 + i) = 0u;
#pragma unroll
    for (int i = 0; i < 4; ++i) creg[i] = 0.f;
  } else {
    if (tid < 256) {
      const int idx = tid * 8, r = idx >> 8, c = idx & 255;
      h8 hv = *(const h8*)(ws_h + (size_t)(b_base + r) * HD + c);
      *(h8*)(h0 + r * 264 + c) = hv;
      unsigned lo = 0, hi = 0;
      lo = __builtin_amdgcn_cvt_pk_fp8_f32((float)hv[0], (float)hv[1], lo, false);
      lo = __builtin_amdgcn_cvt_pk_fp8_f32((float)hv[2], (float)hv[3], lo, true);
      hi = __builtin_amdgcn_cvt_pk_fp8_f32((float)hv[4], (float)hv[5], hi, false);
      hi = __builtin_amdgcn_cvt_pk_fp8_f32((float)hv[6], (float)hv[7], hi, true);
      *(unsigned*)(h80 + r * 264 + c) = lo;
      *(unsigned*)(h80 + r * 264 + c + 4) = hi;
    }
#pragma unroll
    for (int r2 = 0; r2 < 4; ++r2)
      creg[r2] = ws_c[(size_t)(b_base + mrow4 + r2) * HD + c_col];
  }
  __syncthreads();

  // ---- precomputed addressing ----
  // A-fragment row = n&7: rows 8-15 duplicate rows 0-7 (broadcast).
  const int a16_off = (n & 7) * 264 + quad * 8;     // h fp16 read offset (halfs)
  const int a8_off  = (n & 7) * 264 + quad * 8;     // h fp8 read offset (bytes)
  int loff[4];                                       // xq for THIS lane's qi only
#pragma unroll
  for (int g = 0; g < 4; ++g)
    loff[g] = ((g * 256 + c_col) << 4) + bb8 + mrow4;
  const _Float16* xgp = xg + (size_t)(cb >> 1) * (NG * 16);
  float* po[4];
#pragma unroll
  for (int r = 0; r < 4; ++r)
    po[r] = out + ((size_t)(b_base + mrow4 + r) * T_ALL + t0) * HD + c_col;

#pragma unroll 1
  for (int tt = 0; tt < CT; ++tt) {
    // producer readiness (fused mode): every 32 steps check the batch's 32 flags
    // with INDEPENDENT unrolled loads (single pipelined round-trip when ready).
    if (gflags != nullptr && (tt & 31) == 0) {
      const int base = t0 + tt;
      for (;;) {
        int miss = 0;
#pragma unroll
        for (int j = 0; j < 32; ++j)
          miss |= (__hip_atomic_load(&gflags[base + j], __ATOMIC_RELAXED,
                                     __HIP_MEMORY_SCOPE_AGENT) == 0) ? 1 : 0;
        if (!miss) break;
        __builtin_amdgcn_s_sleep(16);
      }
      __threadfence();                 // acquire for the xg data
    }

    const int p = tt & 1;
    const _Float16* hr = (const _Float16*)(smem + SMEM_W + p * SMEM_H);
    const unsigned char* h8r = (const unsigned char*)(smem + SMEM_W + 2 * SMEM_H + p * SMEM_H8);
    _Float16* hw = (_Float16*)(smem + SMEM_W + (p ^ 1) * SMEM_H);
    unsigned char* h8w = (unsigned char*)(smem + SMEM_W + 2 * SMEM_H + (p ^ 1) * SMEM_H8);

    h4 xq[4];
#pragma unroll
    for (int g = 0; g < 4; ++g) xq[g] = *(const h4*)(xgp + loff[g]);

    f4 aI[2], aF[2], aG[2], aO[2];
#pragma unroll
    for (int qi = 0; qi < 2; ++qi) {
      aI[qi][0]=0.f; aI[qi][1]=0.f; aI[qi][2]=0.f; aI[qi][3]=0.f;
      aF[qi][0]=0.f; aF[qi][1]=0.f; aF[qi][2]=0.f; aF[qi][3]=0.f;
      aG[qi][0]=0.f; aG[qi][1]=0.f; aG[qi][2]=0.f; aG[qi][3]=0.f;
      aO[qi][0]=0.f; aO[qi][1]=0.f; aO[qi][2]=0.f; aO[qi][3]=0.f;
    }

    __builtin_amdgcn_s_setprio(1);
#pragma unroll
    for (int kt = 0; kt < 8; ++kt) {
      h8  a16 = *(const h8*)(hr + a16_off + kt * 32);
      long a8 = *(const long*)(h8r + a8_off + kt * 32);
      h8 bg0 = *(const h8*)(w_lds + ((size_t)((2 * w + 0) * 8 + kt) * 64 + L) * 8);
      h8 bg1 = *(const h8*)(w_lds + ((size_t)((2 * w + 1) * 8 + kt) * 64 + L) * 8);
      aF[0] = __builtin_amdgcn_mfma_f32_16x16x32_f16(a16, bF[0][kt], aF[0], 0, 0, 0);
      aF[1] = __builtin_amdgcn_mfma_f32_16x16x32_f16(a16, bF[1][kt], aF[1], 0, 0, 0);
      aG[0] = __builtin_amdgcn_mfma_f32_16x16x32_f16(a16, bg0, aG[0], 0, 0, 0);
      aG[1] = __builtin_amdgcn_mfma_f32_16x16x32_f16(a16, bg1, aG[1], 0, 0, 0);
      aI[0] = __builtin_amdgcn_mfma_f32_16x16x32_fp8_fp8(a8, bI[0][kt], aI[0], 0, 0, 0);
      aI[1] = __builtin_amdgcn_mfma_f32_16x16x32_fp8_fp8(a8, bI[1][kt], aI[1], 0, 0, 0);
      aO[0] = __builtin_amdgcn_mfma_f32_16x16x32_fp8_fp8(a8, bO[0][kt], aO[0], 0, 0, 0);
      aO[1] = __builtin_amdgcn_mfma_f32_16x16x32_fp8_fp8(a8, bO[1][kt], aO[1], 0, 0, 0);
    }
    __builtin_amdgcn_s_setprio(0);

    // Epilogue: 4 outputs/lane (own qi tile via duplicate C-fragments).
    const bool hiq = (L & 32) != 0;
    const f4 sI = hiq ? aI[1] : aI[0];
    const f4 sF = hiq ? aF[1] : aF[0];
    const f4 sG = hiq ? aG[1] : aG[0];
    const f4 sO = hiq ? aO[1] : aO[0];
#pragma unroll
    for (int r = 0; r < 4; ++r) {
      const int row = mrow4 + r;
      const float vi = sI[r] + (float)xq[0][r];
      const float vf = sF[r] + (float)xq[1][r];
      const float vg = sG[r] + (float)xq[2][r];
      const float vo = sO[r] + (float)xq[3][r];
      const float cn = sigf(vf) * creg[r] + sigf(vi) * tanh_f(vg);
      const float hn = sigf(vo) * tanh_f(cn);
      creg[r] = cn;
      hw[row * 264 + c_col] = (_Float16)hn;
      h8w[row * 264 + c_col] = to_fp8(hn);
      __builtin_nontemporal_store(hn, po[r]);
    }
#pragma unroll
    for (int r = 0; r < 4; ++r) po[r] += HD;
    xgp += 4 * NG * 16;

    // LDS-only drain + hardware barrier (round-3 proven): do NOT drain vmcnt.
    asm volatile("s_waitcnt lgkmcnt(0)" ::: "memory");
    __builtin_amdgcn_s_barrier();
    __builtin_amdgcn_sched_barrier(0);
  }

  { // persist state for next chunk + final h_T/c_T
    const int pf = CT & 1;   // buffer holding h(t0+CT-1)
    const _Float16* hfin = (const _Float16*)(smem + SMEM_W + pf * SMEM_H);
    if (tid < 256) {
      const int idx = tid * 8, r = idx >> 8, c = idx & 255;
      h8 hv = *(const h8*)(hfin + r * 264 + c);
      *(h8*)(ws_h + (size_t)(b_base + r) * HD + c) = hv;
      if (t0 + CT == T_ALL) {
        float* ph = out + HS_N + (size_t)(b_base + r) * HD + c;
#pragma unroll
        for (int j = 0; j < 8; ++j) ph[j] = (float)hv[j];
      }
    }
#pragma unroll
    for (int r2 = 0; r2 < 4; ++r2)
      ws_c[(size_t)(b_base + mrow4 + r2) * HD + c_col] = creg[r2];

    if (t0 + CT == T_ALL) {
#pragma unroll
      for (int r2 = 0; r2 < 4; ++r2)
        out[HS_N + (size_t)NBATCH * HD +
            (size_t)(b_base + mrow4 + r2) * HD + c_col] = creg[r2];
    }
  }
}

// ---------------- kernels ----------------
__global__ void clear_flags(int* f) {
  f[blockIdx.x * 1024 + threadIdx.x] = 0;
}

__global__ __launch_bounds__(512, 2) void lstm_fused(
    const float* __restrict__ x, const float* __restrict__ Wi,
    const float* __restrict__ bias, const float* __restrict__ Wh,
    _Float16* __restrict__ xg, float* __restrict__ out,
    _Float16* __restrict__ ws_h, float* __restrict__ ws_c, int* gflags)
{
  extern __shared__ char smem[];
  if (blockIdx.x < NPROD) {
    producer_body(x, Wi, bias, xg, gflags);
  } else {
    recur_body(xg, Wh, out, ws_h, ws_c, gflags, 0, T_ALL, blockIdx.x - NPROD, smem);
  }
}

// fallback path (workspace too small for full-T xg): chunked two-kernel pipeline
__global__ __launch_bounds__(256, 2) void lstm_proj(
    const float* __restrict__ x, const float* __restrict__ Wi,
    const float* __restrict__ bias, _Float16* __restrict__ xg, int t0)
{
  const int t = t0 + blockIdx.x;
  const int tid = threadIdx.x;
  const int w = tid >> 6, L = tid & 63;
  const int n = L & 15, quad = L >> 4;

  h8 bx[8][4];
#pragma unroll
  for (int kt = 0; kt < 8; ++kt) {
#pragma unroll
    for (int bt = 0; bt < 4; ++bt) {
      const int b = bt * 16 + n, k = kt * 32 + quad * 8;
      const float* p = x + ((size_t)b * T_ALL + t) * HD + k;
      f4 lo = *(const f4*)p, hi = *(const f4*)(p + 4);
      h8 f;
      f[0] = (_Float16)lo[0]; f[1] = (_Float16)lo[1];
      f[2] = (_Float16)lo[2]; f[3] = (_Float16)lo[3];
      f[4] = (_Float16)hi[0]; f[5] = (_Float16)hi[1];
      f[6] = (_Float16)hi[2]; f[7] = (_Float16)hi[3];
      bx[kt][bt] = f;
    }
  }

  for (int i = 0; i < 16; ++i) {
    const int jt = w * 16 + i;
    float bv0 = bias[jt * 16 + quad * 4 + 0];
    float bv1 = bias[jt * 16 + quad * 4 + 1];
    float bv2 = bias[jt * 16 + quad * 4 + 2];
    float bv3 = bias[jt * 16 + quad * 4 + 3];
    f4 acc[4];
#pragma unroll
    for (int bt = 0; bt < 4; ++bt) {
      acc[bt][0] = bv0; acc[bt][1] = bv1; acc[bt][2] = bv2; acc[bt][3] = bv3;
    }
#pragma unroll
    for (int kt = 0; kt < 8; ++kt) {
      const int j = jt * 16 + n, kb = kt * 32 + quad * 8;
      h8 a;
#pragma unroll
      for (int jj = 0; jj < 8; ++jj) a[jj] = (_Float16)Wi[(size_t)(kb + jj) * NG + j];
#pragma unroll
      for (int bt = 0; bt < 4; ++bt)
        acc[bt] = __builtin_amdgcn_mfma_f32_16x16x32_f16(a, bx[kt][bt], acc[bt], 0, 0, 0);
    }
#pragma unroll
    for (int bt = 0; bt < 4; ++bt) {
#pragma unroll
      for (int r = 0; r < 4; ++r) {
        const int j = jt * 16 + quad * 4 + r;
        xg[(((size_t)blockIdx.x * 4 + bt) * NG + j) * 16 + n] = (_Float16)acc[bt][r];
      }
    }
  }
}

__global__ __launch_bounds__(512, 2) void lstm_recur(
    const _Float16* __restrict__ xg, const float* __restrict__ Wh,
    float* __restrict__ out, _Float16* __restrict__ ws_h, float* __restrict__ ws_c,
    int t0, int CT)
{
  extern __shared__ char smem[];
  recur_body(xg, Wh, out, ws_h, ws_c, nullptr, t0, CT, blockIdx.x, smem);
}

extern "C" void kernel_launch(void* const* d_in, const int* in_sizes, int n_in,
                              void* d_out, int out_size, void* d_ws, size_t ws_size,
                              hipStream_t stream) {
  (void)in_sizes; (void)n_in; (void)out_size;
  const float* x    = (const float*)d_in[0];
  const float* Wi   = (const float*)d_in[1];
  const float* Wh   = (const float*)d_in[2];
  const float* bias = (const float*)d_in[3];
  float* out = (float*)d_out;

  const size_t state_bytes = (size_t)NBATCH * HD * 2 + (size_t)NBATCH * HD * 4
                           + (size_t)T_ALL * 4;
  int CT = T_ALL;
  while (CT > 32 && (size_t)CT * NG * 64 * 2 + state_bytes > ws_size) CT >>= 1;

  _Float16* xg   = (_Float16*)d_ws;
  _Float16* ws_h = (_Float16*)((char*)d_ws + (size_t)CT * NG * 64 * 2);
  float*    ws_c = (float*)((char*)ws_h + (size_t)NBATCH * HD * 2);
  int*    gflags = (int*)((char*)ws_c + (size_t)NBATCH * HD * 4);

  (void)hipFuncSetAttribute((const void*)lstm_fused,
                            hipFuncAttributeMaxDynamicSharedMemorySize, SMEM_TOTAL);
  (void)hipFuncSetAttribute((const void*)lstm_recur,
                            hipFuncAttributeMaxDynamicSharedMemorySize, SMEM_TOTAL);

  if (CT == T_ALL) {
    clear_flags<<<dim3(2), dim3(1024), 0, stream>>>(gflags);
    lstm_fused<<<dim3(NPROD + 8), dim3(512), SMEM_TOTAL, stream>>>(
        x, Wi, bias, Wh, xg, out, ws_h, ws_c, gflags);
  } else {
    for (int t0 = 0; t0 < T_ALL; t0 += CT) {
      lstm_proj<<<dim3(CT), dim3(256), 0, stream>>>(x, Wi, bias, xg, t0);
      lstm_recur<<<dim3(8), dim3(512), SMEM_TOTAL, stream>>>(xg, Wh, out, ws_h, ws_c, t0, CT);
    }
  }
}

// Round 6
// 4032.503 us; speedup vs baseline: 1.3821x; 1.0584x over previous
//
#include <hip/hip_runtime.h>

// LSTM B=64 T=2048 D=H=256.
// FUSED single launch: 120 producer blocks (x@W_i + bias -> xg, fp16) + 8 consumer
// blocks (persistent recurrence, 8 batch rows each). Producers publish per-timestep
// flags (release fence + agent-scope store); consumers batch-check 32 flags with
// unrolled independent loads every 32 steps (round-5 proven, ~30 cyc/step).
// Consumer weight residency per CU — ROUND-2 layout, now viable because
// amdgpu_waves_per_eu(2,2) unlocks the 256-VGPR/wave budget (LDS already forces
// 1 block/CU = 2 waves/SIMD, so 256 regs costs zero occupancy):
//   gate i: fp8 e4m3 in VGPRs (32) | gate f: fp16 in VGPRs (64)
//   gate g: fp16 in VGPRs (64)     | gate o: fp8 e4m3 in LDS (64 KB, b64 reads)
// This removes the 128x ds_read_b128/step of loop-invariant g-weights (~1536
// cyc/CU/step, 45% of the binding LDS pipe).
// Duplicate-row trick: A row = n&7 -> quads 2-3 duplicate quads 0-1's C; each lane
// finishes 4 outputs (own qi tile) -> halved transcendental VALU.
// h double-buffered in LDS as fp16 AND fp8 (read buf tt&1, write buf tt&1^1).
// Hardware s_barrier per step with lgkmcnt(0)-only drain (no vmcnt drain).
// MFMA 16x16x32 (f16 and fp8_fp8): A[m=lane&15][k=(lane>>4)*8+j],
//   B[k][n=lane&15], C row=(lane>>4)*4+reg, col=lane&15.

#define T_ALL 2048
#define NBATCH 64
#define HD 256
#define NG 1024
#define NPROD 120
#define HS_N ((size_t)NBATCH * T_ALL * HD)

typedef _Float16 h8 __attribute__((ext_vector_type(8)));
typedef _Float16 h4 __attribute__((ext_vector_type(4)));
typedef float f4 __attribute__((ext_vector_type(4)));

#define SMEM_W8 65536                 // o-gate fp8: [16 q][8 kt][64 lanes][8 bytes]
#define SMEM_H 4224                   // h fp16: 8 rows x 264 halfs
#define SMEM_H8 2112                  // h fp8:  8 rows x 264 bytes
#define SMEM_TOTAL (SMEM_W8 + 2 * SMEM_H + 2 * SMEM_H8)   // 78208 <= 163840

__device__ __forceinline__ float sigf(float x) {
  return __builtin_amdgcn_rcpf(1.f + __expf(-x));
}
__device__ __forceinline__ float tanh_f(float x) {
  return 2.f * __builtin_amdgcn_rcpf(1.f + __expf(-2.f * x)) - 1.f;
}
__device__ __forceinline__ unsigned char to_fp8(float x) {
  return (unsigned char)(__builtin_amdgcn_cvt_pk_fp8_f32(x, x, 0, false) & 0xFF);
}
__device__ __forceinline__ int imin2(int a, int b) { return a < b ? a : b; }

// ---------------- producer: input projection for timesteps t = p mod NPROD ----------
__device__ __forceinline__ void producer_body(
    const float* __restrict__ x, const float* __restrict__ Wi,
    const float* __restrict__ bias, _Float16* __restrict__ xg, int* gflags)
{
  const int tid = threadIdx.x;
  const int w = tid >> 6, L = tid & 63;
  const int n = L & 15, quad = L >> 4;

  for (int t = blockIdx.x; t < T_ALL; t += NPROD) {
    // B-fragments: x^T[k][b], reused across all j tiles (32 frags = 128 VGPRs)
    h8 bx[8][4];
#pragma unroll
    for (int kt = 0; kt < 8; ++kt) {
#pragma unroll
      for (int bt = 0; bt < 4; ++bt) {
        const int b = bt * 16 + n, k = kt * 32 + quad * 8;
        const float* p = x + ((size_t)b * T_ALL + t) * HD + k;
        f4 lo = *(const f4*)p, hi = *(const f4*)(p + 4);
        h8 f;
        f[0] = (_Float16)lo[0]; f[1] = (_Float16)lo[1];
        f[2] = (_Float16)lo[2]; f[3] = (_Float16)lo[3];
        f[4] = (_Float16)hi[0]; f[5] = (_Float16)hi[1];
        f[6] = (_Float16)hi[2]; f[7] = (_Float16)hi[3];
        bx[kt][bt] = f;
      }
    }

    for (int i = 0; i < 8; ++i) {      // wave w owns j-tiles w*8 .. w*8+7
      const int jt = w * 8 + i;
      float bv0 = bias[jt * 16 + quad * 4 + 0];
      float bv1 = bias[jt * 16 + quad * 4 + 1];
      float bv2 = bias[jt * 16 + quad * 4 + 2];
      float bv3 = bias[jt * 16 + quad * 4 + 3];
      f4 acc[4];
#pragma unroll
      for (int bt = 0; bt < 4; ++bt) {
        acc[bt][0] = bv0; acc[bt][1] = bv1; acc[bt][2] = bv2; acc[bt][3] = bv3;
      }
#pragma unroll
      for (int kt = 0; kt < 8; ++kt) {
        const int j = jt * 16 + n, kb = kt * 32 + quad * 8;
        h8 a;   // A = Wi^T: A[m=j][k=d] = Wi[d][j]
#pragma unroll
        for (int jj = 0; jj < 8; ++jj) a[jj] = (_Float16)Wi[(size_t)(kb + jj) * NG + j];
#pragma unroll
        for (int bt = 0; bt < 4; ++bt)
          acc[bt] = __builtin_amdgcn_mfma_f32_16x16x32_f16(a, bx[kt][bt], acc[bt], 0, 0, 0);
      }
#pragma unroll
      for (int bt = 0; bt < 4; ++bt) {
#pragma unroll
        for (int r = 0; r < 4; ++r) {
          const int j = jt * 16 + quad * 4 + r;   // gate col
          xg[(((size_t)t * 4 + bt) * NG + j) * 16 + n] = (_Float16)acc[bt][r];
        }
      }
    }
    __syncthreads();                   // all waves' xg stores drained (vmcnt 0)
    if (tid == 0) {
      __threadfence();                 // agent-scope release: L2 writeback
      __hip_atomic_store(&gflags[t], 1, __ATOMIC_RELAXED, __HIP_MEMORY_SCOPE_AGENT);
    }
  }
}

// ---------------- consumer: persistent recurrence, 8 batch rows per block ----------
__device__ __forceinline__ void recur_body(
    const _Float16* __restrict__ xg, const float* __restrict__ Wh,
    float* __restrict__ out, _Float16* __restrict__ ws_h, float* __restrict__ ws_c,
    const int* gflags, int t0, int CT, int cb, char* smem)
{
  unsigned char* w8_lds = (unsigned char*)smem;                   // o-gate fp8 tiles

  const int tid = threadIdx.x;
  const int w = tid >> 6, L = tid & 63;
  const int n = L & 15, quad = L >> 4;
  const int myqi = L >> 5;             // 0 for quads 0-1, 1 for quads 2-3
  const int mrow4 = ((L >> 4) & 1) * 4;
  const int b_base = cb * 8;
  const int bb8 = (cb & 1) * 8;        // row offset within the 16-batch xg tile

  // ---- load resident weights (one-time) ----
  h8  bF[2][8];                    // f gate fp16: 64 VGPRs
  h8  bG[2][8];                    // g gate fp16: 64 VGPRs
  long bI[2][8];                   // i gate fp8 packed: 32 VGPRs
#pragma unroll
  for (int qi = 0; qi < 2; ++qi) {
    const int q = 2 * w + qi;
    for (int kt = 0; kt < 8; ++kt) {
      const int kb = kt * 32 + quad * 8;
      { // f gate, fp16 regs
        const int j = 256 + q * 16 + n;
        h8 f;
#pragma unroll
        for (int jj = 0; jj < 8; ++jj) f[jj] = (_Float16)Wh[(size_t)(kb + jj) * NG + j];
        bF[qi][kt] = f;
      }
      { // g gate, fp16 regs
        const int j = 512 + q * 16 + n;
        h8 f;
#pragma unroll
        for (int jj = 0; jj < 8; ++jj) f[jj] = (_Float16)Wh[(size_t)(kb + jj) * NG + j];
        bG[qi][kt] = f;
      }
      { // i gate, fp8 regs
        const int j = 0 + q * 16 + n;
        unsigned lo = 0, hi = 0;
        lo = __builtin_amdgcn_cvt_pk_fp8_f32(Wh[(size_t)(kb + 0) * NG + j], Wh[(size_t)(kb + 1) * NG + j], lo, false);
        lo = __builtin_amdgcn_cvt_pk_fp8_f32(Wh[(size_t)(kb + 2) * NG + j], Wh[(size_t)(kb + 3) * NG + j], lo, true);
        hi = __builtin_amdgcn_cvt_pk_fp8_f32(Wh[(size_t)(kb + 4) * NG + j], Wh[(size_t)(kb + 5) * NG + j], hi, false);
        hi = __builtin_amdgcn_cvt_pk_fp8_f32(Wh[(size_t)(kb + 6) * NG + j], Wh[(size_t)(kb + 7) * NG + j], hi, true);
        bI[qi][kt] = (long)(((unsigned long)hi << 32) | (unsigned long)lo);
      }
      { // o gate, fp8 -> LDS
        const int j = 768 + q * 16 + n;
        unsigned lo = 0, hi = 0;
        lo = __builtin_amdgcn_cvt_pk_fp8_f32(Wh[(size_t)(kb + 0) * NG + j], Wh[(size_t)(kb + 1) * NG + j], lo, false);
        lo = __builtin_amdgcn_cvt_pk_fp8_f32(Wh[(size_t)(kb + 2) * NG + j], Wh[(size_t)(kb + 3) * NG + j], lo, true);
        hi = __builtin_amdgcn_cvt_pk_fp8_f32(Wh[(size_t)(kb + 4) * NG + j], Wh[(size_t)(kb + 5) * NG + j], hi, false);
        hi = __builtin_amdgcn_cvt_pk_fp8_f32(Wh[(size_t)(kb + 6) * NG + j], Wh[(size_t)(kb + 7) * NG + j], hi, true);
        *(unsigned long*)(w8_lds + ((size_t)(q * 8 + kt) * 64 + L) * 8) =
            ((unsigned long)hi << 32) | (unsigned long)lo;
      }
    }
  }

  // ---- state init / restore (into buffer 0: read buffer of step tt=0) ----
  _Float16* h0 = (_Float16*)(smem + SMEM_W8);
  unsigned char* h80 = (unsigned char*)(smem + SMEM_W8 + 2 * SMEM_H);
  float creg[4];                    // lane-private c: row=mrow4+r, col=(2w+myqi)*16+n
  const int c_col = (2 * w + myqi) * 16 + n;
  if (t0 == 0) {
    for (int i = tid; i < 8 * 264; i += 512) h0[i] = (_Float16)0.f;
    for (int i = tid * 4; i < 8 * 264; i += 512 * 4) *(unsigned*)(h80 + i) = 0u;
#pragma unroll
    for (int i = 0; i < 4; ++i) creg[i] = 0.f;
  } else {
    if (tid < 256) {
      const int idx = tid * 8, r = idx >> 8, c = idx & 255;
      h8 hv = *(const h8*)(ws_h + (size_t)(b_base + r) * HD + c);
      *(h8*)(h0 + r * 264 + c) = hv;
      unsigned lo = 0, hi = 0;
      lo = __builtin_amdgcn_cvt_pk_fp8_f32((float)hv[0], (float)hv[1], lo, false);
      lo = __builtin_amdgcn_cvt_pk_fp8_f32((float)hv[2], (float)hv[3], lo, true);
      hi = __builtin_amdgcn_cvt_pk_fp8_f32((float)hv[4], (float)hv[5], hi, false);
      hi = __builtin_amdgcn_cvt_pk_fp8_f32((float)hv[6], (float)hv[7], hi, true);
      *(unsigned*)(h80 + r * 264 + c) = lo;
      *(unsigned*)(h80 + r * 264 + c + 4) = hi;
    }
#pragma unroll
    for (int r2 = 0; r2 < 4; ++r2)
      creg[r2] = ws_c[(size_t)(b_base + mrow4 + r2) * HD + c_col];
  }
  __syncthreads();

  // ---- precomputed addressing ----
  // A-fragment row = n&7: rows 8-15 duplicate rows 0-7 (broadcast).
  const int a16_off = (n & 7) * 264 + quad * 8;     // h fp16 read offset (halfs)
  const int a8_off  = (n & 7) * 264 + quad * 8;     // h fp8 read offset (bytes)
  const int o8_off0 = (((2 * w + 0) * 8) * 64 + L) * 8;   // o-gate LDS, qi=0, kt=0
  const int o8_off1 = (((2 * w + 1) * 8) * 64 + L) * 8;   // o-gate LDS, qi=1, kt=0
  int loff[4];                                       // xq for THIS lane's qi only
#pragma unroll
  for (int g = 0; g < 4; ++g)
    loff[g] = ((g * 256 + c_col) << 4) + bb8 + mrow4;
  const _Float16* xgp = xg + (size_t)(cb >> 1) * (NG * 16);
  float* po[4];
#pragma unroll
  for (int r = 0; r < 4; ++r)
    po[r] = out + ((size_t)(b_base + mrow4 + r) * T_ALL + t0) * HD + c_col;

#pragma unroll 1
  for (int tt = 0; tt < CT; ++tt) {
    // producer readiness (fused mode): every 32 steps check the batch's 32 flags
    // with INDEPENDENT unrolled loads (single pipelined round-trip when ready).
    if (gflags != nullptr && (tt & 31) == 0) {
      const int base = t0 + tt;
      for (;;) {
        int miss = 0;
#pragma unroll
        for (int j = 0; j < 32; ++j)
          miss |= (__hip_atomic_load(&gflags[base + j], __ATOMIC_RELAXED,
                                     __HIP_MEMORY_SCOPE_AGENT) == 0) ? 1 : 0;
        if (!miss) break;
        __builtin_amdgcn_s_sleep(16);
      }
      __threadfence();                 // acquire for the xg data
    }

    const int p = tt & 1;
    const _Float16* hr = (const _Float16*)(smem + SMEM_W8 + p * SMEM_H);
    const unsigned char* h8r = (const unsigned char*)(smem + SMEM_W8 + 2 * SMEM_H + p * SMEM_H8);
    _Float16* hw = (_Float16*)(smem + SMEM_W8 + (p ^ 1) * SMEM_H);
    unsigned char* h8w = (unsigned char*)(smem + SMEM_W8 + 2 * SMEM_H + (p ^ 1) * SMEM_H8);

    h4 xq[4];
#pragma unroll
    for (int g = 0; g < 4; ++g) xq[g] = *(const h4*)(xgp + loff[g]);

    f4 aI[2], aF[2], aG[2], aO[2];
#pragma unroll
    for (int qi = 0; qi < 2; ++qi) {
      aI[qi][0]=0.f; aI[qi][1]=0.f; aI[qi][2]=0.f; aI[qi][3]=0.f;
      aF[qi][0]=0.f; aF[qi][1]=0.f; aF[qi][2]=0.f; aF[qi][3]=0.f;
      aG[qi][0]=0.f; aG[qi][1]=0.f; aG[qi][2]=0.f; aG[qi][3]=0.f;
      aO[qi][0]=0.f; aO[qi][1]=0.f; aO[qi][2]=0.f; aO[qi][3]=0.f;
    }

    __builtin_amdgcn_s_setprio(1);
#pragma unroll
    for (int kt = 0; kt < 8; ++kt) {
      h8  a16 = *(const h8*)(hr + a16_off + kt * 32);
      long a8 = *(const long*)(h8r + a8_off + kt * 32);
      long o80 = *(const long*)(w8_lds + o8_off0 + kt * 512);
      long o81 = *(const long*)(w8_lds + o8_off1 + kt * 512);
      aF[0] = __builtin_amdgcn_mfma_f32_16x16x32_f16(a16, bF[0][kt], aF[0], 0, 0, 0);
      aF[1] = __builtin_amdgcn_mfma_f32_16x16x32_f16(a16, bF[1][kt], aF[1], 0, 0, 0);
      aG[0] = __builtin_amdgcn_mfma_f32_16x16x32_f16(a16, bG[0][kt], aG[0], 0, 0, 0);
      aG[1] = __builtin_amdgcn_mfma_f32_16x16x32_f16(a16, bG[1][kt], aG[1], 0, 0, 0);
      aI[0] = __builtin_amdgcn_mfma_f32_16x16x32_fp8_fp8(a8, bI[0][kt], aI[0], 0, 0, 0);
      aI[1] = __builtin_amdgcn_mfma_f32_16x16x32_fp8_fp8(a8, bI[1][kt], aI[1], 0, 0, 0);
      aO[0] = __builtin_amdgcn_mfma_f32_16x16x32_fp8_fp8(a8, o80, aO[0], 0, 0, 0);
      aO[1] = __builtin_amdgcn_mfma_f32_16x16x32_fp8_fp8(a8, o81, aO[1], 0, 0, 0);
    }
    __builtin_amdgcn_s_setprio(0);

    // Epilogue: 4 outputs/lane (own qi tile via duplicate C-fragments).
    const bool hiq = (L & 32) != 0;
    const f4 sI = hiq ? aI[1] : aI[0];
    const f4 sF = hiq ? aF[1] : aF[0];
    const f4 sG = hiq ? aG[1] : aG[0];
    const f4 sO = hiq ? aO[1] : aO[0];
#pragma unroll
    for (int r = 0; r < 4; ++r) {
      const int row = mrow4 + r;
      const float vi = sI[r] + (float)xq[0][r];
      const float vf = sF[r] + (float)xq[1][r];
      const float vg = sG[r] + (float)xq[2][r];
      const float vo = sO[r] + (float)xq[3][r];
      const float cn = sigf(vf) * creg[r] + sigf(vi) * tanh_f(vg);
      const float hn = sigf(vo) * tanh_f(cn);
      creg[r] = cn;
      hw[row * 264 + c_col] = (_Float16)hn;
      h8w[row * 264 + c_col] = to_fp8(hn);
      __builtin_nontemporal_store(hn, po[r]);
    }
#pragma unroll
    for (int r = 0; r < 4; ++r) po[r] += HD;
    xgp += 4 * NG * 16;

    // LDS-only drain + hardware barrier: do NOT drain vmcnt.
    asm volatile("s_waitcnt lgkmcnt(0)" ::: "memory");
    __builtin_amdgcn_s_barrier();
    __builtin_amdgcn_sched_barrier(0);
  }

  { // persist state for next chunk + final h_T/c_T
    const int pf = CT & 1;   // buffer holding h(t0+CT-1)
    const _Float16* hfin = (const _Float16*)(smem + SMEM_W8 + pf * SMEM_H);
    if (tid < 256) {
      const int idx = tid * 8, r = idx >> 8, c = idx & 255;
      h8 hv = *(const h8*)(hfin + r * 264 + c);
      *(h8*)(ws_h + (size_t)(b_base + r) * HD + c) = hv;
      if (t0 + CT == T_ALL) {
        float* ph = out + HS_N + (size_t)(b_base + r) * HD + c;
#pragma unroll
        for (int j = 0; j < 8; ++j) ph[j] = (float)hv[j];
      }
    }
#pragma unroll
    for (int r2 = 0; r2 < 4; ++r2)
      ws_c[(size_t)(b_base + mrow4 + r2) * HD + c_col] = creg[r2];

    if (t0 + CT == T_ALL) {
#pragma unroll
      for (int r2 = 0; r2 < 4; ++r2)
        out[HS_N + (size_t)NBATCH * HD +
            (size_t)(b_base + mrow4 + r2) * HD + c_col] = creg[r2];
    }
  }
}

// ---------------- kernels ----------------
__global__ void clear_flags(int* f) {
  f[blockIdx.x * 1024 + threadIdx.x] = 0;
}

__global__ __attribute__((amdgpu_waves_per_eu(2, 2))) __launch_bounds__(512)
void lstm_fused(
    const float* __restrict__ x, const float* __restrict__ Wi,
    const float* __restrict__ bias, const float* __restrict__ Wh,
    _Float16* __restrict__ xg, float* __restrict__ out,
    _Float16* __restrict__ ws_h, float* __restrict__ ws_c, int* gflags)
{
  extern __shared__ char smem[];
  if (blockIdx.x < NPROD) {
    producer_body(x, Wi, bias, xg, gflags);
  } else {
    recur_body(xg, Wh, out, ws_h, ws_c, gflags, 0, T_ALL, blockIdx.x - NPROD, smem);
  }
}

// fallback path (workspace too small for full-T xg): chunked two-kernel pipeline
__global__ __launch_bounds__(256, 2) void lstm_proj(
    const float* __restrict__ x, const float* __restrict__ Wi,
    const float* __restrict__ bias, _Float16* __restrict__ xg, int t0)
{
  const int t = t0 + blockIdx.x;
  const int tid = threadIdx.x;
  const int w = tid >> 6, L = tid & 63;
  const int n = L & 15, quad = L >> 4;

  h8 bx[8][4];
#pragma unroll
  for (int kt = 0; kt < 8; ++kt) {
#pragma unroll
    for (int bt = 0; bt < 4; ++bt) {
      const int b = bt * 16 + n, k = kt * 32 + quad * 8;
      const float* p = x + ((size_t)b * T_ALL + t) * HD + k;
      f4 lo = *(const f4*)p, hi = *(const f4*)(p + 4);
      h8 f;
      f[0] = (_Float16)lo[0]; f[1] = (_Float16)lo[1];
      f[2] = (_Float16)lo[2]; f[3] = (_Float16)lo[3];
      f[4] = (_Float16)hi[0]; f[5] = (_Float16)hi[1];
      f[6] = (_Float16)hi[2]; f[7] = (_Float16)hi[3];
      bx[kt][bt] = f;
    }
  }

  for (int i = 0; i < 16; ++i) {
    const int jt = w * 16 + i;
    float bv0 = bias[jt * 16 + quad * 4 + 0];
    float bv1 = bias[jt * 16 + quad * 4 + 1];
    float bv2 = bias[jt * 16 + quad * 4 + 2];
    float bv3 = bias[jt * 16 + quad * 4 + 3];
    f4 acc[4];
#pragma unroll
    for (int bt = 0; bt < 4; ++bt) {
      acc[bt][0] = bv0; acc[bt][1] = bv1; acc[bt][2] = bv2; acc[bt][3] = bv3;
    }
#pragma unroll
    for (int kt = 0; kt < 8; ++kt) {
      const int j = jt * 16 + n, kb = kt * 32 + quad * 8;
      h8 a;
#pragma unroll
      for (int jj = 0; jj < 8; ++jj) a[jj] = (_Float16)Wi[(size_t)(kb + jj) * NG + j];
#pragma unroll
      for (int bt = 0; bt < 4; ++bt)
        acc[bt] = __builtin_amdgcn_mfma_f32_16x16x32_f16(a, bx[kt][bt], acc[bt], 0, 0, 0);
    }
#pragma unroll
    for (int bt = 0; bt < 4; ++bt) {
#pragma unroll
      for (int r = 0; r < 4; ++r) {
        const int j = jt * 16 + quad * 4 + r;
        xg[(((size_t)blockIdx.x * 4 + bt) * NG + j) * 16 + n] = (_Float16)acc[bt][r];
      }
    }
  }
}

__global__ __attribute__((amdgpu_waves_per_eu(2, 2))) __launch_bounds__(512)
void lstm_recur(
    const _Float16* __restrict__ xg, const float* __restrict__ Wh,
    float* __restrict__ out, _Float16* __restrict__ ws_h, float* __restrict__ ws_c,
    int t0, int CT)
{
  extern __shared__ char smem[];
  recur_body(xg, Wh, out, ws_h, ws_c, nullptr, t0, CT, blockIdx.x, smem);
}

extern "C" void kernel_launch(void* const* d_in, const int* in_sizes, int n_in,
                              void* d_out, int out_size, void* d_ws, size_t ws_size,
                              hipStream_t stream) {
  (void)in_sizes; (void)n_in; (void)out_size;
  const float* x    = (const float*)d_in[0];
  const float* Wi   = (const float*)d_in[1];
  const float* Wh   = (const float*)d_in[2];
  const float* bias = (const float*)d_in[3];
  float* out = (float*)d_out;

  const size_t state_bytes = (size_t)NBATCH * HD * 2 + (size_t)NBATCH * HD * 4
                           + (size_t)T_ALL * 4;
  int CT = T_ALL;
  while (CT > 32 && (size_t)CT * NG * 64 * 2 + state_bytes > ws_size) CT >>= 1;

  _Float16* xg   = (_Float16*)d_ws;
  _Float16* ws_h = (_Float16*)((char*)d_ws + (size_t)CT * NG * 64 * 2);
  float*    ws_c = (float*)((char*)ws_h + (size_t)NBATCH * HD * 2);
  int*    gflags = (int*)((char*)ws_c + (size_t)NBATCH * HD * 4);

  (void)hipFuncSetAttribute((const void*)lstm_fused,
                            hipFuncAttributeMaxDynamicSharedMemorySize, SMEM_TOTAL);
  (void)hipFuncSetAttribute((const void*)lstm_recur,
                            hipFuncAttributeMaxDynamicSharedMemorySize, SMEM_TOTAL);

  if (CT == T_ALL) {
    clear_flags<<<dim3(2), dim3(1024), 0, stream>>>(gflags);
    lstm_fused<<<dim3(NPROD + 8), dim3(512), SMEM_TOTAL, stream>>>(
        x, Wi, bias, Wh, xg, out, ws_h, ws_c, gflags);
  } else {
    for (int t0 = 0; t0 < T_ALL; t0 += CT) {
      lstm_proj<<<dim3(CT), dim3(256), 0, stream>>>(x, Wi, bias, xg, t0);
      lstm_recur<<<dim3(8), dim3(512), SMEM_TOTAL, stream>>>(xg, Wh, out, ws_h, ws_c, t0, CT);
    }
  }
}